// Round 14
// baseline (2650.129 us; speedup 1.0000x reference)
//
#include <hip/hip_runtime.h>

#define D 128
#define NEIGH 16
#define SINKI 20
#define TINYF 1e-30f

typedef __attribute__((ext_vector_type(8))) _Float16 f16x8;
typedef __attribute__((ext_vector_type(4))) float f32x4;
typedef __attribute__((ext_vector_type(2))) unsigned int u32x2;

// DPP rotate within 16-lane row: ror by N lanes; chain of 4 = broadcast row sum.
template <int N>
__device__ __forceinline__ float rorf(float v) {
  int r = __builtin_amdgcn_update_dpp(0, __builtin_bit_cast(int, v),
                                      0x120 + N, 0xf, 0xf, true);
  return __builtin_bit_cast(float, r);
}

// U row k (256B), byte-swizzle ^((k&15)<<4); read 16B e-slice (ks,g)
__device__ __forceinline__ f16x8 ldfrag(const _Float16* U, int k, int ks, int g) {
  return *(const f16x8*)((const char*)U + k * 256 + (((ks << 6) + (g << 4)) ^ ((k & 15) << 4)));
}

// write U[k][d0..d0+3], d0 = 16rt+4g, same swizzle; RTE casts
__device__ __forceinline__ void stquad(_Float16* U, int k, int rt, int g,
                                       float x, float y, float z, float w) {
  union { _Float16 h[4]; u32x2 u; } P;
  P.h[0] = (_Float16)x; P.h[1] = (_Float16)y;
  P.h[2] = (_Float16)z; P.h[3] = (_Float16)w;
  *(u32x2*)((char*)U + k * 256 + (((rt << 5) + (g << 3)) ^ ((k & 15) << 4))) = P.u;
}

// block = 512 thr = 8 slots (1 wave each); each slot processes a PAIR of nodes.
// U rows: 0..15 = node-A neighbors, 16..31 = node-B neighbors, 32 = self A,
// 33 = self B, 34 = permanent zero row (pad reads), 35 = unused pad.
// LDS = KB(32K) + KA(32K) + 8*9K = 136 KB. K-tables are kernel-invariant:
// KB rt=0..3 (16 frags) + KA rt=0 (4 frags) persist in VGPRs (loaded once) --
// occupancy is LDS-capped at 2 waves/SIMD, so the +80 VGPR is free.
__global__ __launch_bounds__(512, 1)
void wgcn_hop(const float* __restrict__ Xin,
              const float* __restrict__ Cmat,
              const int* __restrict__ neigh,
              float* __restrict__ Xout,
              int n_pairs) {
  __shared__ _Float16 KB[16384];   // MM1 A-frags: Khat[e=32ks+8g+s][d=16rt+c]
  __shared__ _Float16 KA[16384];   // MM2 A-frags: Khat[d=16rt+c][e=32ks+8g+s]
  __shared__ _Float16 US[8][4608]; // 36 rows x 128 f16 per slot

  const int tid = threadIdx.x;

  for (int idx = tid; idx < 16384; idx += 512) {
    const int s = idx & 7, c = (idx >> 3) & 15, g = (idx >> 7) & 3;
    const int rt = (idx >> 9) & 7, ks = idx >> 12;
    const int e = (ks << 5) + (g << 3) + s;
    const int d = (rt << 4) + c;
    KB[idx] = (_Float16)(16.0f * expf(-10.0f * Cmat[e * 128 + d]));
    KA[idx] = (_Float16)(16.0f * expf(-10.0f * Cmat[d * 128 + e]));
  }
  __syncthreads();

  const int slot = tid >> 6;
  const int lane = tid & 63;
  const int g = lane >> 4;
  const int c = lane & 15;
  const int cc = (c < 2) ? c : 2;          // tile2 read-row offset (row 34 = zeros)
  _Float16* U = US[slot];

  // persistent register-resident K fragments (kernel-invariant)
  f16x8 KBreg[4][4], KAreg0[4];
#pragma unroll
  for (int rt = 0; rt < 4; ++rt)
#pragma unroll
    for (int ks = 0; ks < 4; ++ks)
      KBreg[rt][ks] = *(const f16x8*)&KB[((((ks << 3) + rt) << 6) + lane) << 3];
#pragma unroll
  for (int ks = 0; ks < 4; ++ks)
    KAreg0[ks] = *(const f16x8*)&KA[(((ks << 3) << 6) + lane) << 3];

  // rows 34/35: permanent zeros, init once
  ((unsigned int*)U)[(34 << 6) | lane] = 0u;
  ((unsigned int*)U)[(35 << 6) | lane] = 0u;

  for (int p = blockIdx.x * 8 + slot; p < n_pairs; p += gridDim.x * 8) {
    const int nA = 2 * p, nB = 2 * p + 1;

    // ---- gather mu for A-neighbors, B-neighbors, selves; normalize ----
    f32x4 mu0[8], mu1[8], muS[8], bvA[8], bvB[8];
    const int srcA = neigh[nA * NEIGH + c];
    const int srcB = neigh[nB * NEIGH + c];
    const int srcS = (c == 1) ? nB : nA;   // c==0 -> A, c==1 -> B, c>=2 dummy
#pragma unroll
    for (int rt = 0; rt < 8; ++rt) {
      mu0[rt] = *(const f32x4*)&Xin[(long)srcA * D + rt * 16 + g * 4];
      mu1[rt] = *(const f32x4*)&Xin[(long)srcB * D + rt * 16 + g * 4];
      muS[rt] = *(const f32x4*)&Xin[(long)srcS * D + rt * 16 + g * 4];
    }
    float s0 = 0.f, s1 = 0.f, sS = 0.f;
#pragma unroll
    for (int rt = 0; rt < 8; ++rt) {
      s0 += mu0[rt].x + mu0[rt].y + mu0[rt].z + mu0[rt].w;
      s1 += mu1[rt].x + mu1[rt].y + mu1[rt].z + mu1[rt].w;
      sS += muS[rt].x + muS[rt].y + muS[rt].z + muS[rt].w;
    }
    s0 += __shfl_xor(s0, 16, 64); s0 += __shfl_xor(s0, 32, 64);
    s1 += __shfl_xor(s1, 16, 64); s1 += __shfl_xor(s1, 32, 64);
    sS += __shfl_xor(sS, 16, 64); sS += __shfl_xor(sS, 32, 64);
    const float i0 = 1024.0f * __builtin_amdgcn_rcpf(s0 + TINYF);
    const float i1 = 1024.0f * __builtin_amdgcn_rcpf(s1 + TINYF);
    const float iS = 1024.0f * __builtin_amdgcn_rcpf(sS + TINYF);
#pragma unroll
    for (int rt = 0; rt < 8; ++rt) {
      mu0[rt].x *= i0; mu0[rt].y *= i0; mu0[rt].z *= i0; mu0[rt].w *= i0;
      mu1[rt].x *= i1; mu1[rt].y *= i1; mu1[rt].z *= i1; mu1[rt].w *= i1;
      muS[rt].x *= iS; muS[rt].y *= iS; muS[rt].z *= iS; muS[rt].w *= iS;
    }

    // ---- u0 = 1 on real rows 0..33 ----
#pragma unroll
    for (int j = 0; j < 34; ++j)
      ((unsigned int*)U)[(j << 6) | lane] = 0x3C003C00u;
    asm volatile("s_waitcnt lgkmcnt(0)" ::: "memory");

#pragma unroll 1
    for (int it = 0; it < SINKI; ++it) {
      // ======== MM1': KTu'[d][k] = sum_e Khat[e][d] * u[k][e] ========
      f16x8 b0[4], b1[4], b2[4];
#pragma unroll
      for (int ks = 0; ks < 4; ++ks) {
        b0[ks] = ldfrag(U, c, ks, g);
        b1[ks] = ldfrag(U, 16 + c, ks, g);
        b2[ks] = ldfrag(U, 32 + cc, ks, g);
      }
#pragma unroll
      for (int rt = 0; rt < 8; ++rt) {
        f32x4 a0 = {0.f, 0.f, 0.f, 0.f}, a1 = a0, a2 = a0;
#pragma unroll
        for (int ks = 0; ks < 4; ++ks) {
          const f16x8 af = (rt < 4) ? KBreg[rt][ks]
              : *(const f16x8*)&KB[((((ks << 3) + rt) << 6) + lane) << 3];
          a0 = __builtin_amdgcn_mfma_f32_16x16x32_f16(af, b0[ks], a0, 0, 0, 0);
          a1 = __builtin_amdgcn_mfma_f32_16x16x32_f16(af, b1[ks], a1, 0, 0, 0);
          a2 = __builtin_amdgcn_mfma_f32_16x16x32_f16(af, b2[ks], a2, 0, 0, 0);
        }
        stquad(U, c, rt, g,
               mu0[rt].x * __builtin_amdgcn_rcpf(a0.x),
               mu0[rt].y * __builtin_amdgcn_rcpf(a0.y),
               mu0[rt].z * __builtin_amdgcn_rcpf(a0.z),
               mu0[rt].w * __builtin_amdgcn_rcpf(a0.w));
        stquad(U, 16 + c, rt, g,
               mu1[rt].x * __builtin_amdgcn_rcpf(a1.x),
               mu1[rt].y * __builtin_amdgcn_rcpf(a1.y),
               mu1[rt].z * __builtin_amdgcn_rcpf(a1.z),
               mu1[rt].w * __builtin_amdgcn_rcpf(a1.w));
        if (c < 2)
          stquad(U, 32 + c, rt, g,
                 muS[rt].x * __builtin_amdgcn_rcpf(a2.x),
                 muS[rt].y * __builtin_amdgcn_rcpf(a2.y),
                 muS[rt].z * __builtin_amdgcn_rcpf(a2.z),
                 muS[rt].w * __builtin_amdgcn_rcpf(a2.w));
      }
      asm volatile("s_waitcnt lgkmcnt(0)" ::: "memory");

      // ======== MM2': Kv'[d][k] = sum_e Khat[d][e] * v[k][e] ========
#pragma unroll
      for (int ks = 0; ks < 4; ++ks) {
        b0[ks] = ldfrag(U, c, ks, g);
        b1[ks] = ldfrag(U, 16 + c, ks, g);
        b2[ks] = ldfrag(U, 32 + cc, ks, g);
      }
#pragma unroll
      for (int rt = 0; rt < 8; ++rt) {
        f32x4 a0 = {0.f, 0.f, 0.f, 0.f}, a1 = a0, a2 = a0;
#pragma unroll
        for (int ks = 0; ks < 4; ++ks) {
          const f16x8 af = (rt == 0) ? KAreg0[ks]
              : *(const f16x8*)&KA[((((ks << 3) + rt) << 6) + lane) << 3];
          a0 = __builtin_amdgcn_mfma_f32_16x16x32_f16(af, b0[ks], a0, 0, 0, 0);
          a1 = __builtin_amdgcn_mfma_f32_16x16x32_f16(af, b1[ks], a1, 0, 0, 0);
          a2 = __builtin_amdgcn_mfma_f32_16x16x32_f16(af, b2[ks], a2, 0, 0, 0);
        }
        float bA[4], bB[4];
#pragma unroll
        for (int r = 0; r < 4; ++r) {
          const float tA = ((const float*)&a0)[r];
          const float tB = ((const float*)&a1)[r];
          const float tS = ((const float*)&a2)[r];
          float fA = (c == 0) ? tA * tS : tA;   // fold self-A into lane c==0
          float fB = (c == 1) ? tB * tS : tB;   // fold self-B into lane c==1
          float pA = __builtin_amdgcn_logf(fA);
          float pB = __builtin_amdgcn_logf(fB);
          pA += rorf<1>(pA); pA += rorf<2>(pA); pA += rorf<4>(pA); pA += rorf<8>(pA);
          pB += rorf<1>(pB); pB += rorf<2>(pB); pB += rorf<4>(pB); pB += rorf<8>(pB);
          bA[r] = __builtin_amdgcn_exp2f(pA * (1.0f / 17.0f));
          bB[r] = __builtin_amdgcn_exp2f(pB * (1.0f / 17.0f));
        }
        bvA[rt].x = bA[0]; bvA[rt].y = bA[1]; bvA[rt].z = bA[2]; bvA[rt].w = bA[3];
        bvB[rt].x = bB[0]; bvB[rt].y = bB[1]; bvB[rt].z = bB[2]; bvB[rt].w = bB[3];
        stquad(U, c, rt, g,
               bA[0] * __builtin_amdgcn_rcpf(((const float*)&a0)[0]),
               bA[1] * __builtin_amdgcn_rcpf(((const float*)&a0)[1]),
               bA[2] * __builtin_amdgcn_rcpf(((const float*)&a0)[2]),
               bA[3] * __builtin_amdgcn_rcpf(((const float*)&a0)[3]));
        stquad(U, 16 + c, rt, g,
               bB[0] * __builtin_amdgcn_rcpf(((const float*)&a1)[0]),
               bB[1] * __builtin_amdgcn_rcpf(((const float*)&a1)[1]),
               bB[2] * __builtin_amdgcn_rcpf(((const float*)&a1)[2]),
               bB[3] * __builtin_amdgcn_rcpf(((const float*)&a1)[3]));
        if (c < 2) {
          const float q0 = ((c == 0) ? bA[0] : bB[0]) * __builtin_amdgcn_rcpf(((const float*)&a2)[0]);
          const float q1 = ((c == 0) ? bA[1] : bB[1]) * __builtin_amdgcn_rcpf(((const float*)&a2)[1]);
          const float q2 = ((c == 0) ? bA[2] : bB[2]) * __builtin_amdgcn_rcpf(((const float*)&a2)[2]);
          const float q3 = ((c == 0) ? bA[3] : bB[3]) * __builtin_amdgcn_rcpf(((const float*)&a2)[3]);
          stquad(U, 32 + c, rt, g, q0, q1, q2, q3);
        }
      }
      asm volatile("s_waitcnt lgkmcnt(0)" ::: "memory");
    }

    // ---- output: lane c==0 -> node A, c==1 -> node B; b = bhat/1024 (f32 path) ----
    if (c < 2) {
      float* dst = &Xout[(long)((c == 0) ? nA : nB) * D];
#pragma unroll
      for (int rt = 0; rt < 8; ++rt) {
        const f32x4 bq = (c == 0) ? bvA[rt] : bvB[rt];
        f32x4 o;
        o.x = bq.x * (1.0f / 1024.0f);
        o.y = bq.y * (1.0f / 1024.0f);
        o.z = bq.z * (1.0f / 1024.0f);
        o.w = bq.w * (1.0f / 1024.0f);
        *(f32x4*)&dst[rt * 16 + g * 4] = o;
      }
    }
  }
}

extern "C" void kernel_launch(void* const* d_in, const int* in_sizes, int n_in,
                              void* d_out, int out_size, void* d_ws, size_t ws_size,
                              hipStream_t stream) {
  const float* trans_X = (const float*)d_in[0];
  const float* cost = (const float*)d_in[1];
  const int* neigh = (const int*)d_in[2];
  float* out = (float*)d_out;
  float* X1 = (float*)d_ws;   // intermediate hop output, 20000*128 f32
  const int n = in_sizes[0] / D;
  const int n_pairs = n / 2;  // N = 20000 even

  // 250 blocks x 8 slots = 2000 slots -> exactly 5 pairs per slot
  dim3 grid(250), block(512);
  hipLaunchKernelGGL(wgcn_hop, grid, block, 0, stream, trans_X, cost, neigh, X1, n_pairs);
  hipLaunchKernelGGL(wgcn_hop, grid, block, 0, stream, X1, cost, neigh, out, n_pairs);
}

// Round 15
// 1640.924 us; speedup vs baseline: 1.6150x; 1.6150x over previous
//
#include <hip/hip_runtime.h>

#define D 128
#define NEIGH 16
#define SINKI 20
#define TINYF 1e-30f

typedef __attribute__((ext_vector_type(8))) _Float16 f16x8;
typedef __attribute__((ext_vector_type(2))) _Float16 f16x2;
typedef __attribute__((ext_vector_type(4))) float f32x4;
typedef __attribute__((ext_vector_type(2))) unsigned int u32x2;

// DPP rotate within 16-lane row: ror by N lanes, accumulate -> full row sum.
template <int N>
__device__ __forceinline__ float rorf(float v) {
  int r = __builtin_amdgcn_update_dpp(0, __builtin_bit_cast(int, v),
                                      0x120 + N, 0xf, 0xf, true);
  return __builtin_bit_cast(float, r);
}

// U row k (256B), byte-swizzle ^((k&15)<<4); read 16B e-slice (ks,g)
__device__ __forceinline__ f16x8 ldfrag(const _Float16* U, int k, int ks, int g) {
  return *(const f16x8*)((const char*)U + k * 256 + (((ks << 6) + (g << 4)) ^ ((k & 15) << 4)));
}

// write U[k][d0..d0+3], d0 = 16rt+4g, same swizzle; RTE casts
__device__ __forceinline__ void stquad(_Float16* U, int k, int rt, int g,
                                       float x, float y, float z, float w) {
  union { _Float16 h[4]; u32x2 u; } P;
  P.h[0] = (_Float16)x; P.h[1] = (_Float16)y;
  P.h[2] = (_Float16)z; P.h[3] = (_Float16)w;
  *(u32x2*)((char*)U + k * 256 + (((rt << 5) + (g << 3)) ^ ((k & 15) << 4))) = P.u;
}

// block = 512 thr = 8 slots (1 wave each); each slot processes a PAIR of nodes.
// U rows: 0..15 = node-A neighbors, 16..31 = node-B neighbors, 32 = self A,
// 33 = self B, 34 = permanent zero row (pad reads), 35 = unused pad.
// LDS = KB(32K) + KA(32K) + 8*9K = 136 KB.
// No TINY in the iteration epilogues: real elements are bounded away from 0
// (x + 1e-30 == x bitwise for x > 1e-23), and pad zeros produce +inf only in
// exec-masked writes (rows 34/35 are init-once, never rewritten).
__global__ __launch_bounds__(512, 1)
void wgcn_hop(const float* __restrict__ Xin,
              const float* __restrict__ Cmat,
              const int* __restrict__ neigh,
              float* __restrict__ Xout,
              int n_pairs) {
  __shared__ _Float16 KB[16384];   // MM1 A-frags: Khat[e=32ks+8g+s][d=16rt+c]
  __shared__ _Float16 KA[16384];   // MM2 A-frags: Khat[d=16rt+c][e=32ks+8g+s]
  __shared__ _Float16 US[8][4608]; // 36 rows x 128 f16 per slot

  const int tid = threadIdx.x;

  for (int idx = tid; idx < 16384; idx += 512) {
    const int s = idx & 7, c = (idx >> 3) & 15, g = (idx >> 7) & 3;
    const int rt = (idx >> 9) & 7, ks = idx >> 12;
    const int e = (ks << 5) + (g << 3) + s;
    const int d = (rt << 4) + c;
    KB[idx] = (_Float16)(16.0f * expf(-10.0f * Cmat[e * 128 + d]));
    KA[idx] = (_Float16)(16.0f * expf(-10.0f * Cmat[d * 128 + e]));
  }
  __syncthreads();

  const int slot = tid >> 6;
  const int lane = tid & 63;
  const int g = lane >> 4;
  const int c = lane & 15;
  const int cc = (c < 2) ? c : 2;          // tile2 read-row offset (row 34 = zeros)
  _Float16* U = US[slot];

  // rows 34/35: permanent zeros, init once
  ((unsigned int*)U)[(34 << 6) | lane] = 0u;
  ((unsigned int*)U)[(35 << 6) | lane] = 0u;

  for (int p = blockIdx.x * 8 + slot; p < n_pairs; p += gridDim.x * 8) {
    const int nA = 2 * p, nB = 2 * p + 1;

    // ---- gather mu for A-neighbors, B-neighbors, selves; normalize ----
    f32x4 mu0[8], mu1[8], muS[8], bvA[8], bvB[8];
    const int srcA = neigh[nA * NEIGH + c];
    const int srcB = neigh[nB * NEIGH + c];
    const int srcS = (c == 1) ? nB : nA;   // c==0 -> A, c==1 -> B, c>=2 dummy
#pragma unroll
    for (int rt = 0; rt < 8; ++rt) {
      mu0[rt] = *(const f32x4*)&Xin[(long)srcA * D + rt * 16 + g * 4];
      mu1[rt] = *(const f32x4*)&Xin[(long)srcB * D + rt * 16 + g * 4];
      muS[rt] = *(const f32x4*)&Xin[(long)srcS * D + rt * 16 + g * 4];
    }
    float s0 = 0.f, s1 = 0.f, sS = 0.f;
#pragma unroll
    for (int rt = 0; rt < 8; ++rt) {
      s0 += mu0[rt].x + mu0[rt].y + mu0[rt].z + mu0[rt].w;
      s1 += mu1[rt].x + mu1[rt].y + mu1[rt].z + mu1[rt].w;
      sS += muS[rt].x + muS[rt].y + muS[rt].z + muS[rt].w;
    }
    s0 += __shfl_xor(s0, 16, 64); s0 += __shfl_xor(s0, 32, 64);
    s1 += __shfl_xor(s1, 16, 64); s1 += __shfl_xor(s1, 32, 64);
    sS += __shfl_xor(sS, 16, 64); sS += __shfl_xor(sS, 32, 64);
    const float i0 = 1024.0f * __builtin_amdgcn_rcpf(s0 + TINYF);
    const float i1 = 1024.0f * __builtin_amdgcn_rcpf(s1 + TINYF);
    const float iS = 1024.0f * __builtin_amdgcn_rcpf(sS + TINYF);
#pragma unroll
    for (int rt = 0; rt < 8; ++rt) {
      mu0[rt].x *= i0; mu0[rt].y *= i0; mu0[rt].z *= i0; mu0[rt].w *= i0;
      mu1[rt].x *= i1; mu1[rt].y *= i1; mu1[rt].z *= i1; mu1[rt].w *= i1;
      muS[rt].x *= iS; muS[rt].y *= iS; muS[rt].z *= iS; muS[rt].w *= iS;
    }

    // ---- u0 = 1 on real rows 0..33 ----
#pragma unroll
    for (int j = 0; j < 34; ++j)
      ((unsigned int*)U)[(j << 6) | lane] = 0x3C003C00u;

    // preload MM1 rt=0 A-frags (loop-invariant K; ready after the fence)
    f16x8 pre1[4], pre2[4];
#pragma unroll
    for (int ks = 0; ks < 4; ++ks)
      pre1[ks] = *(const f16x8*)&KB[(((ks << 3) << 6) + lane) << 3];

    asm volatile("s_waitcnt lgkmcnt(0)" ::: "memory");

#pragma unroll 1
    for (int it = 0; it < SINKI; ++it) {
      // ======== MM1': KTu'[d][k] = sum_e Khat[e][d] * u[k][e] ========
      f16x8 b0[4], b1[4], b2[4];
#pragma unroll
      for (int ks = 0; ks < 4; ++ks) {
        b0[ks] = ldfrag(U, c, ks, g);
        b1[ks] = ldfrag(U, 16 + c, ks, g);
        b2[ks] = ldfrag(U, 32 + cc, ks, g);
      }
#pragma unroll
      for (int rt = 0; rt < 8; ++rt) {
        f32x4 a0 = {0.f, 0.f, 0.f, 0.f}, a1 = a0, a2 = a0;
#pragma unroll
        for (int ks = 0; ks < 4; ++ks) {
          const f16x8 af = (rt == 0) ? pre1[ks]
              : *(const f16x8*)&KB[((((ks << 3) + rt) << 6) + lane) << 3];
          a0 = __builtin_amdgcn_mfma_f32_16x16x32_f16(af, b0[ks], a0, 0, 0, 0);
          a1 = __builtin_amdgcn_mfma_f32_16x16x32_f16(af, b1[ks], a1, 0, 0, 0);
          a2 = __builtin_amdgcn_mfma_f32_16x16x32_f16(af, b2[ks], a2, 0, 0, 0);
        }
        stquad(U, c, rt, g,
               mu0[rt].x * __builtin_amdgcn_rcpf(a0.x),
               mu0[rt].y * __builtin_amdgcn_rcpf(a0.y),
               mu0[rt].z * __builtin_amdgcn_rcpf(a0.z),
               mu0[rt].w * __builtin_amdgcn_rcpf(a0.w));
        stquad(U, 16 + c, rt, g,
               mu1[rt].x * __builtin_amdgcn_rcpf(a1.x),
               mu1[rt].y * __builtin_amdgcn_rcpf(a1.y),
               mu1[rt].z * __builtin_amdgcn_rcpf(a1.z),
               mu1[rt].w * __builtin_amdgcn_rcpf(a1.w));
        if (c < 2)
          stquad(U, 32 + c, rt, g,
                 muS[rt].x * __builtin_amdgcn_rcpf(a2.x),
                 muS[rt].y * __builtin_amdgcn_rcpf(a2.y),
                 muS[rt].z * __builtin_amdgcn_rcpf(a2.z),
                 muS[rt].w * __builtin_amdgcn_rcpf(a2.w));
      }
      // preload MM2 rt=0 A-frags before the fence
#pragma unroll
      for (int ks = 0; ks < 4; ++ks)
        pre2[ks] = *(const f16x8*)&KA[(((ks << 3) << 6) + lane) << 3];
      asm volatile("s_waitcnt lgkmcnt(0)" ::: "memory");

      // ======== MM2': Kv'[d][k] = sum_e Khat[d][e] * v[k][e] ========
#pragma unroll
      for (int ks = 0; ks < 4; ++ks) {
        b0[ks] = ldfrag(U, c, ks, g);
        b1[ks] = ldfrag(U, 16 + c, ks, g);
        b2[ks] = ldfrag(U, 32 + cc, ks, g);
      }
#pragma unroll
      for (int rt = 0; rt < 8; ++rt) {
        f32x4 a0 = {0.f, 0.f, 0.f, 0.f}, a1 = a0, a2 = a0;
#pragma unroll
        for (int ks = 0; ks < 4; ++ks) {
          const f16x8 af = (rt == 0) ? pre2[ks]
              : *(const f16x8*)&KA[((((ks << 3) + rt) << 6) + lane) << 3];
          a0 = __builtin_amdgcn_mfma_f32_16x16x32_f16(af, b0[ks], a0, 0, 0, 0);
          a1 = __builtin_amdgcn_mfma_f32_16x16x32_f16(af, b1[ks], a1, 0, 0, 0);
          a2 = __builtin_amdgcn_mfma_f32_16x16x32_f16(af, b2[ks], a2, 0, 0, 0);
        }
        float bA[4], bB[4];
#pragma unroll
        for (int r = 0; r < 4; ++r) {
          const float tA = ((const float*)&a0)[r];
          const float tB = ((const float*)&a1)[r];
          const float tS = ((const float*)&a2)[r];
          float fA = (c == 0) ? tA * tS : tA;   // fold self-A into lane c==0
          float fB = (c == 1) ? tB * tS : tB;   // fold self-B into lane c==1
          float pA = __builtin_amdgcn_logf(fA);
          float pB = __builtin_amdgcn_logf(fB);
          pA += rorf<1>(pA); pA += rorf<2>(pA); pA += rorf<4>(pA); pA += rorf<8>(pA);
          pB += rorf<1>(pB); pB += rorf<2>(pB); pB += rorf<4>(pB); pB += rorf<8>(pB);
          bA[r] = __builtin_amdgcn_exp2f(pA * (1.0f / 17.0f));
          bB[r] = __builtin_amdgcn_exp2f(pB * (1.0f / 17.0f));
        }
        bvA[rt].x = bA[0]; bvA[rt].y = bA[1]; bvA[rt].z = bA[2]; bvA[rt].w = bA[3];
        bvB[rt].x = bB[0]; bvB[rt].y = bB[1]; bvB[rt].z = bB[2]; bvB[rt].w = bB[3];
        stquad(U, c, rt, g,
               bA[0] * __builtin_amdgcn_rcpf(((const float*)&a0)[0]),
               bA[1] * __builtin_amdgcn_rcpf(((const float*)&a0)[1]),
               bA[2] * __builtin_amdgcn_rcpf(((const float*)&a0)[2]),
               bA[3] * __builtin_amdgcn_rcpf(((const float*)&a0)[3]));
        stquad(U, 16 + c, rt, g,
               bB[0] * __builtin_amdgcn_rcpf(((const float*)&a1)[0]),
               bB[1] * __builtin_amdgcn_rcpf(((const float*)&a1)[1]),
               bB[2] * __builtin_amdgcn_rcpf(((const float*)&a1)[2]),
               bB[3] * __builtin_amdgcn_rcpf(((const float*)&a1)[3]));
        if (c < 2) {
          const float q0 = ((c == 0) ? bA[0] : bB[0]) * __builtin_amdgcn_rcpf(((const float*)&a2)[0]);
          const float q1 = ((c == 0) ? bA[1] : bB[1]) * __builtin_amdgcn_rcpf(((const float*)&a2)[1]);
          const float q2 = ((c == 0) ? bA[2] : bB[2]) * __builtin_amdgcn_rcpf(((const float*)&a2)[2]);
          const float q3 = ((c == 0) ? bA[3] : bB[3]) * __builtin_amdgcn_rcpf(((const float*)&a2)[3]);
          stquad(U, 32 + c, rt, g, q0, q1, q2, q3);
        }
      }
      // preload MM1 rt=0 A-frags for the next iteration before the fence
#pragma unroll
      for (int ks = 0; ks < 4; ++ks)
        pre1[ks] = *(const f16x8*)&KB[(((ks << 3) << 6) + lane) << 3];
      asm volatile("s_waitcnt lgkmcnt(0)" ::: "memory");
    }

    // ---- output: lane c==0 -> node A, c==1 -> node B; b = bhat/1024 (f32 path) ----
    if (c < 2) {
      float* dst = &Xout[(long)((c == 0) ? nA : nB) * D];
#pragma unroll
      for (int rt = 0; rt < 8; ++rt) {
        const f32x4 bq = (c == 0) ? bvA[rt] : bvB[rt];
        f32x4 o;
        o.x = bq.x * (1.0f / 1024.0f);
        o.y = bq.y * (1.0f / 1024.0f);
        o.z = bq.z * (1.0f / 1024.0f);
        o.w = bq.w * (1.0f / 1024.0f);
        *(f32x4*)&dst[rt * 16 + g * 4] = o;
      }
    }
  }
}

extern "C" void kernel_launch(void* const* d_in, const int* in_sizes, int n_in,
                              void* d_out, int out_size, void* d_ws, size_t ws_size,
                              hipStream_t stream) {
  const float* trans_X = (const float*)d_in[0];
  const float* cost = (const float*)d_in[1];
  const int* neigh = (const int*)d_in[2];
  float* out = (float*)d_out;
  float* X1 = (float*)d_ws;   // intermediate hop output, 20000*128 f32
  const int n = in_sizes[0] / D;
  const int n_pairs = n / 2;  // N = 20000 even

  // 250 blocks x 8 slots = 2000 slots -> exactly 5 pairs per slot
  dim3 grid(250), block(512);
  hipLaunchKernelGGL(wgcn_hop, grid, block, 0, stream, trans_X, cost, neigh, X1, n_pairs);
  hipLaunchKernelGGL(wgcn_hop, grid, block, 0, stream, X1, cost, neigh, out, n_pairs);
}